// Round 14
// baseline (315.395 us; speedup 1.0000x reference)
//
#include <hip/hip_runtime.h>
#include <math.h>

#define BN 8192
#define ENC 256
#define NCL 32
#define TM 128
#define BK 32
#define CCAP 1024
#define SCOL 2048   // sample column base
#define SN 256      // sample column count
#define RCAP 24     // per-row per-tile LDS candidate cap (Poisson lambda~4)

typedef __attribute__((ext_vector_type(8))) short short8;   // bf16x8 fragment
typedef __attribute__((ext_vector_type(4))) float f32x4;
typedef __attribute__((ext_vector_type(4))) unsigned uint4v;

__device__ __forceinline__ ushort f2bf(float x) {           // RNE float->bf16
    unsigned b = __float_as_uint(x);
    return (ushort)((b + 0x7FFFu + ((b >> 16) & 1u)) >> 16);
}

__device__ __forceinline__ void async16(void* lds, const void* g) {
    __builtin_amdgcn_global_load_lds(
        (const __attribute__((address_space(1))) unsigned*)g,
        (__attribute__((address_space(3))) unsigned*)lds, 16, 0, 0);
}

// ---------------- K1: sumsq + cat argmax + bf16 hi/lo split + ccnt zero ---------------
__global__ void prep_kernel(const float* __restrict__ enc, const float* __restrict__ cat,
                            float* __restrict__ sq, float* __restrict__ maxg,
                            int* __restrict__ hard, ushort* __restrict__ eh,
                            ushort* __restrict__ el, int* __restrict__ ccnt) {
    int w = threadIdx.x >> 6, l = threadIdx.x & 63;
    int row = blockIdx.x * 4 + w;
    int gid = blockIdx.x * 256 + threadIdx.x;
    if (gid < BN) ccnt[gid] = 0;       // candidate counters re-zeroed every launch

    const float4* e4 = (const float4*)(enc + (size_t)row * ENC);
    float4 v = e4[l];  // elements 4l..4l+3
    float s = v.x * v.x + v.y * v.y + v.z * v.z + v.w * v.w;
    for (int m = 32; m; m >>= 1) s += __shfl_xor(s, m, 64);

    ushort4 hh, ll;
    hh.x = f2bf(v.x); ll.x = f2bf(v.x - __uint_as_float((unsigned)hh.x << 16));
    hh.y = f2bf(v.y); ll.y = f2bf(v.y - __uint_as_float((unsigned)hh.y << 16));
    hh.z = f2bf(v.z); ll.z = f2bf(v.z - __uint_as_float((unsigned)hh.z << 16));
    hh.w = f2bf(v.w); ll.w = f2bf(v.w - __uint_as_float((unsigned)hh.w << 16));
    int g = l >> 1;                                       // original granule 0..31
    int gs = (g & ~3) | ((g & 3) ^ ((row >> 1) & 3));     // swizzled within group-of-4
    int kp = gs * 8 + (l & 1) * 4;                        // element offset in row
    *(ushort4*)(eh + (size_t)row * ENC + kp) = hh;
    *(ushort4*)(el + (size_t)row * ENC + kp) = ll;

    float cv = (l < NCL) ? cat[(size_t)row * NCL + l] : -__builtin_huge_valf();
    int ci = (l < NCL) ? l : 0x7fffffff;
    for (int m = 32; m; m >>= 1) {
        float ov = __shfl_xor(cv, m, 64);
        int oi = __shfl_xor(ci, m, 64);
        if (ov > cv || (ov == cv && oi < ci)) { cv = ov; ci = oi; }
    }
    if (l == 0) { sq[row] = s; maxg[row] = cv; hard[row] = ci; }
}

// ---------------- K2: fused split-bf16 MFMA d2 + candidate filter ---------------------
// Round-13 PMC: MfmaUtil 30% == MFMA-cycles / LDS-pipe-cycles -> LDS-throughput
// bound (64KB reads + 32KB stage per block-K-step vs ~233 cyc MFMA). This round:
// A fragments load DIRECTLY global->register (contiguous 16B per lane, L2-hot
// under the column-strip map) with ping-pong prefetch; LDS stages B only.
// LDS reads halve, stage writes halve. d2 still never materialized.
__global__ __launch_bounds__(256, 2)
void dist_mfma_kernel(const ushort* __restrict__ eh, const ushort* __restrict__ el,
                      const float* __restrict__ sq, int mode,
                      float* __restrict__ samp, const unsigned* __restrict__ piv,
                      unsigned* __restrict__ cval, int* __restrict__ cidxb,
                      int* __restrict__ ccnt) {
    __shared__ __align__(16) ushort ldsB[2][2 * TM * BK];  // 2 bufs x 16KB (Bh Bl)

    int t = threadIdx.x, w = t >> 6, l = t & 63;
    int wm = w >> 1, wn = w & 1;

    int bx, by;
    if (mode) {  // column-strip XCD map: per-XCD working set = A panel + B strip (L2-fit)
        int gx = gridDim.x;
        int bid = blockIdx.y * gx + blockIdx.x;
        int xcd = bid & 7, i = bid >> 3;
        int strip = gx >> 3;
        bx = xcd * strip + (i % strip);
        by = i / strip;
    } else { bx = blockIdx.x; by = blockIdx.y; }

    int gi0 = by * TM;                         // A rows
    int j0 = (mode ? 0 : SCOL) + bx * TM;      // B rows / d2 cols

    f32x4 acc[4][4];
#pragma unroll
    for (int m = 0; m < 4; ++m)
#pragma unroll
        for (int n = 0; n < 4; ++n) acc[m][n] = (f32x4){0.f, 0.f, 0.f, 0.f};

    int srow = w * 32 + (l >> 2);      // staging row (+ q*16), wave covers 32 rows
    int sg = (l & 3) * 8;              // granule elem offset within K-slice

#define STAGE(BUF, K0)                                                        \
    do {                                                                      \
        _Pragma("unroll") for (int q_ = 0; q_ < 2; ++q_) {                    \
            int r_ = srow + q_ * 16;                                          \
            size_t gb_ = (size_t)(j0 + r_) * ENC + (K0) + sg;                 \
            int ldo_ = r_ * BK + sg;                                          \
            async16(&ldsB[BUF][0 * TM * BK + ldo_], eh + gb_);                \
            async16(&ldsB[BUF][1 * TM * BK + ldo_], el + gb_);                \
        }                                                                     \
    } while (0)

    // A-direct: per-lane contiguous 16B at the swizzled granule (un-swizzle on read)
    short8 ah[2][4], al[2][4];
#define LOADA(PB, K0)                                                         \
    do {                                                                      \
        _Pragma("unroll") for (int m_ = 0; m_ < 4; ++m_) {                    \
            int R_ = gi0 + wm * 64 + m_ * 16 + (l & 15);                      \
            size_t ga_ = (size_t)R_ * ENC + (K0)                              \
                       + (size_t)(((l >> 4) ^ ((R_ >> 1) & 3)) * 8);          \
            ah[PB][m_] = *(const short8*)(eh + ga_);                          \
            al[PB][m_] = *(const short8*)(el + ga_);                          \
        }                                                                     \
    } while (0)

    LOADA(0, 0);
    STAGE(0, 0);
    __syncthreads();                   // prologue: first B tile ready

#pragma unroll
    for (int ks = 0; ks < 8; ++ks) {   // fully unrolled: all buf/reg indices static
        int k0 = ks * BK;
        int cb = ks & 1, nb = cb ^ 1;
        if (ks + 1 < 8) {
            STAGE(nb, k0 + BK);        // issue next B tile + next A frags FIRST
            LOADA(nb, k0 + BK);        // (land under this step's MFMA cluster)
        }

        const ushort* Bh = &ldsB[cb][0];
        const ushort* Bl = Bh + TM * BK;
        short8 bh[4], bl4[4];
#pragma unroll
        for (int n = 0; n < 4; ++n) {
            int R = wn * 64 + n * 16 + (l & 15);
            int gl = (l >> 4) ^ ((R >> 1) & 3);       // un-swizzle on read
            bh[n]  = *(const short8*)(Bh + R * BK + gl * 8);
            bl4[n] = *(const short8*)(Bl + R * BK + gl * 8);
        }
        // swapped operands: D[col=l&15 -> d2 row][reg -> d2 col]
#pragma unroll
        for (int m = 0; m < 4; ++m)
#pragma unroll
            for (int n = 0; n < 4; ++n) {
                acc[m][n] = __builtin_amdgcn_mfma_f32_16x16x32_bf16(bh[n],  ah[cb][m], acc[m][n], 0, 0, 0);
                acc[m][n] = __builtin_amdgcn_mfma_f32_16x16x32_bf16(bl4[n], ah[cb][m], acc[m][n], 0, 0, 0);
                acc[m][n] = __builtin_amdgcn_mfma_f32_16x16x32_bf16(bh[n],  al[cb][m], acc[m][n], 0, 0, 0);
            }

        __syncthreads();               // one barrier/step: drains next-tile loads
    }
#undef STAGE
#undef LOADA

    // epilogue: row = gi0 + wm*64 + m*16 + (l&15); col = j0 + wn*64 + n*16 + q4 + r
    int il = l & 15, q4 = (l >> 4) * 4;
    float sqi[4];
    float sqj[4][4];
#pragma unroll
    for (int m = 0; m < 4; ++m) sqi[m] = sq[gi0 + wm * 64 + m * 16 + il];
#pragma unroll
    for (int n = 0; n < 4; ++n)
#pragma unroll
        for (int r = 0; r < 4; ++r) sqj[n][r] = sq[j0 + wn * 64 + n * 16 + q4 + r];

    if (!mode) {
#pragma unroll
        for (int m = 0; m < 4; ++m)
#pragma unroll
            for (int n = 0; n < 4; ++n) {
                float4 o;
                o.x = fmaxf(sqi[m] + sqj[n][0] - 2.f * acc[m][n][0], 0.f);
                o.y = fmaxf(sqi[m] + sqj[n][1] - 2.f * acc[m][n][1], 0.f);
                o.z = fmaxf(sqi[m] + sqj[n][2] - 2.f * acc[m][n][2], 0.f);
                o.w = fmaxf(sqi[m] + sqj[n][3] - 2.f * acc[m][n][3], 0.f);
                int row = gi0 + wm * 64 + m * 16 + il;
                int jc = j0 + wn * 64 + n * 16 + q4;
                *(float4*)(samp + (size_t)row * SN + (jc - SCOL)) = o;
            }
        return;
    }

    // ---- mode 1: LDS-aggregated candidate flush (overlay on idle staging LDS) ----
    int* rcnt = (int*)&ldsB[0][0];                 // [128] per-local-row counts
    int* rbase = rcnt + TM;                        // [128] reserved global bases
    unsigned* bval = (unsigned*)(rbase + TM);      // [128][RCAP]
    int* bidx = (int*)(bval + TM * RCAP);          // [128][RCAP]  (total ~25 KB)

    if (t < TM) rcnt[t] = 0;
    unsigned pv[4];
#pragma unroll
    for (int m = 0; m < 4; ++m) pv[m] = piv[gi0 + wm * 64 + m * 16 + il];
    __syncthreads();                   // rcnt zeroed; K-loop LDS reads long done

#pragma unroll
    for (int m = 0; m < 4; ++m)
#pragma unroll
        for (int n = 0; n < 4; ++n) {
            int lr = wm * 64 + m * 16 + il;        // local row 0..127
            int jc = j0 + wn * 64 + n * 16 + q4;
#pragma unroll
            for (int r = 0; r < 4; ++r) {
                float o = fmaxf(sqi[m] + sqj[n][r] - 2.f * acc[m][n][r], 0.f);
                unsigned ub = __float_as_uint(o);
                if (ub < pv[m]) {                  // ~2 hits/thread: LDS atomic
                    int pos = atomicAdd(&rcnt[lr], 1);
                    if (pos < RCAP) {
                        bval[lr * RCAP + pos] = ub;
                        bidx[lr * RCAP + pos] = jc + r;
                    } else {                       // overflow ~never: direct, exact
                        int slot = atomicAdd(&ccnt[gi0 + lr], 1);
                        if (slot < CCAP) {
                            cval[(size_t)(gi0 + lr) * CCAP + slot] = ub;
                            cidxb[(size_t)(gi0 + lr) * CCAP + slot] = jc + r;
                        }
                    }
                }
            }
        }
    __syncthreads();

    if (t < TM) {                      // 128 PARALLEL global atomics (latency overlap)
        int c = rcnt[t]; if (c > RCAP) c = RCAP;
        rbase[t] = c ? atomicAdd(&ccnt[gi0 + t], c) : 0;
    }
    __syncthreads();

    {                                  // coalesced copy-out: 2 threads per row
        int lr = t >> 1;
        int c = rcnt[lr]; if (c > RCAP) c = RCAP;
        int b = rbase[lr];
        for (int e = t & 1; e < c; e += 2) {
            int s = b + e;
            if (s < CCAP) {
                cval[(size_t)(gi0 + lr) * CCAP + s] = bval[lr * RCAP + e];
                cidxb[(size_t)(gi0 + lr) * CCAP + s] = bidx[lr * RCAP + e];
            }
        }
    }
}

// ---------------- K2b: per-row pivot = rank-r of 256 sampled d2 -----------------------
__global__ void pivot_kernel(const float* __restrict__ samp, const int* __restrict__ kptr,
                             unsigned* __restrict__ piv) {
    int w = threadIdx.x >> 6, l = threadIdx.x & 63;
    int row = blockIdx.x * 4 + w;
    const uint4v* rd = (const uint4v*)(samp + (size_t)row * SN);
    uint4v sv = rd[l];

    int topn = *kptr + 1;
    int r = topn / 16 + 1; if (r < 8) r = 8;   // E[row count] ~ 32r ~ 255

    unsigned lo = 0u, hi = 0x7F800000u;        // d2 >= 0: uint order == float order
    while (lo < hi) {                          // wave-uniform, no block sync
        unsigned mid = lo + ((hi - lo) >> 1);
        int c = 0;
#pragma unroll
        for (int e = 0; e < 4; ++e) c += __popcll(__ballot(sv[e] <= mid));
        if (c >= r) hi = mid; else lo = mid + 1;
    }
    if (l == 0) piv[row] = lo;
}

// ---------------- K3: exact rank-26 among candidates + bins + entropy -----------------
__global__ __launch_bounds__(256, 2)
void select_kernel(const unsigned* __restrict__ cval, const int* __restrict__ cidxb,
                   const int* __restrict__ ccnt, const unsigned* __restrict__ piv,
                   const float* __restrict__ enc, const float* __restrict__ sq,
                   const float* __restrict__ maxg, const int* __restrict__ hard,
                   const int* __restrict__ kptr, float* __restrict__ out) {
    __shared__ __align__(16) unsigned sval[CCAP];
    __shared__ int sidx[CCAP];
    __shared__ __align__(16) unsigned rowbuf[BN];   // fallback only (32 KB)
    __shared__ __align__(16) float encrow[ENC];
    __shared__ int scnt[2][4];
    __shared__ int sbins[NCL];

    int t = threadIdx.x, w = t >> 6, l = t & 63;
    int li = blockIdx.x;
    if (t < NCL) sbins[t] = 0;

    int topn = *kptr + 1;              // 26: thr = sorted[k]
    int nc = ccnt[li];
    bool ok = (nc >= topn) && (nc <= CCAP);
    unsigned thr;

    if (ok) {
#pragma unroll
        for (int k2 = 0; k2 < 4; ++k2) sval[t + k2 * 256] = 0xFFFFFFFFu;  // pad
        for (int pos = t; pos < nc; pos += 256) {     // same-thread slots: no race
            sval[pos] = cval[(size_t)li * CCAP + pos];
            sidx[pos] = cidxb[(size_t)li * CCAP + pos];
        }
        __syncthreads();

        int pp = 0;
        unsigned lo = 0u, hi = piv[li];               // all candidates < piv
        while (lo < hi) {
            unsigned mid = lo + ((hi - lo) >> 1);
            uint4v cv = ((const uint4v*)sval)[t];     // 1 ds_read_b128/thread/probe
            int cnt = 0;
#pragma unroll
            for (int c = 0; c < 4; ++c) cnt += __popcll(__ballot(cv[c] <= mid));
            if (l == 0) scnt[pp][w] = cnt;
            __syncthreads();                          // parity slots: 1 barrier/probe
            int tot = scnt[pp][0] + scnt[pp][1] + scnt[pp][2] + scnt[pp][3];
            if (tot >= topn) hi = mid; else lo = mid + 1;
            pp ^= 1;
        }
        thr = lo;

        for (int pos = t; pos < nc; pos += 256)
            if (sval[pos] < thr) atomicAdd(&sbins[hard[sidx[pos]]], 1);
    } else {
        // exact fallback: fp32 full-row recompute + block bisection (round-9 proven)
        if (t < 64) ((float4*)encrow)[t] = ((const float4*)(enc + (size_t)li * ENC))[t];
        __syncthreads();
        float sqi = sq[li];
        for (int c0 = 0; c0 < BN; c0 += 256) {
            int c = c0 + t;
            const float* ec = enc + (size_t)c * ENC;
            float dot = 0.f;
            for (int d = 0; d < ENC; ++d) dot = fmaf(encrow[d], ec[d], dot);
            rowbuf[c] = __float_as_uint(fmaxf(sqi + sq[c] - 2.f * dot, 0.f));
        }
        __syncthreads();

        int pp = 0;
        unsigned lo = 0u, hi = 0x7F800000u;
        while (lo < hi) {
            unsigned mid = lo + ((hi - lo) >> 1);
            int cnt = 0;
#pragma unroll
            for (int q = 0; q < 8; ++q) {
                uint4v u = ((const uint4v*)rowbuf)[q * 256 + t];
#pragma unroll
                for (int c = 0; c < 4; ++c) cnt += __popcll(__ballot(u[c] <= mid));
            }
            if (l == 0) scnt[pp][w] = cnt;
            __syncthreads();
            int tot = scnt[pp][0] + scnt[pp][1] + scnt[pp][2] + scnt[pp][3];
            if (tot >= topn) hi = mid; else lo = mid + 1;
            pp ^= 1;
        }
        thr = lo;

#pragma unroll
        for (int q = 0; q < 8; ++q) {
            uint4v u = ((const uint4v*)rowbuf)[q * 256 + t];
#pragma unroll
            for (int c = 0; c < 4; ++c)
                if (u[c] < thr)
                    atomicAdd(&sbins[hard[(q * 256 + t) * 4 + c]], 1);
        }
    }
    __syncthreads();

    // entropy epilogue: wave 0, lanes 0..31 = clusters
    if (t < NCL) {
        int cnt = sbins[t];
        int n = cnt;
        for (int m = 16; m; m >>= 1) n += __shfl_xor(n, m, 64);
        float nf = (float)n;
        float b = (float)cnt / nf;
        float term = -b * logf(b + 1e-5f);
        for (int m = 16; m; m >>= 1) term += __shfl_xor(term, m, 64);
        if (t == 0) out[li] = term * maxg[li];
    }
}

extern "C" void kernel_launch(void* const* d_in, const int* in_sizes, int n_in,
                              void* d_out, int out_size, void* d_ws, size_t ws_size,
                              hipStream_t stream) {
    const float* enc = (const float*)d_in[0];
    const float* cat = (const float*)d_in[1];
    const int* kptr = (const int*)d_in[2];
    float* out = (float*)d_out;

    float* sq = (float*)d_ws;                               // 32 KB
    float* maxg = sq + BN;                                  // 32 KB
    int* hard = (int*)(maxg + BN);                          // 32 KB
    ushort* eh = (ushort*)(hard + BN);                      // 4 MB
    ushort* el = eh + (size_t)BN * ENC;                     // 4 MB
    float* samp = (float*)(el + (size_t)BN * ENC);          // 8 MB
    unsigned* piv = (unsigned*)(samp + (size_t)BN * SN);    // 32 KB
    int* ccnt = (int*)(piv + BN);                           // 32 KB
    unsigned* cval = (unsigned*)(ccnt + BN);                // 32 MB
    int* cidxb = (int*)(cval + (size_t)BN * CCAP);          // 32 MB

    prep_kernel<<<BN / 4, 256, 0, stream>>>(enc, cat, sq, maxg, hard, eh, el, ccnt);

    dim3 gs(SN / TM, BN / TM);        // sample pass: 2 x 64 tiles
    dist_mfma_kernel<<<gs, 256, 0, stream>>>(eh, el, sq, 0, samp, piv, cval, cidxb, ccnt);

    pivot_kernel<<<BN / 4, 256, 0, stream>>>(samp, kptr, piv);

    dim3 gm(BN / TM, BN / TM);        // main pass: 64 x 64 tiles, no d2 store
    dist_mfma_kernel<<<gm, 256, 0, stream>>>(eh, el, sq, 1, samp, piv, cval, cidxb, ccnt);

    select_kernel<<<BN, 256, 0, stream>>>(cval, cidxb, ccnt, piv, enc, sq,
                                          maxg, hard, kptr, out);
}

// Round 15
// 315.362 us; speedup vs baseline: 1.0001x; 1.0001x over previous
//
#include <hip/hip_runtime.h>
#include <math.h>

#define BN 8192
#define ENC 256
#define NCL 32
#define BM 256      // block tile (256x256), 8 waves 2x4, wave tile 128x64
#define BK 32
#define CCAP 1024
#define SCOL 2048   // sample column base
#define SN 256      // sample column count
#define RCAP 24     // per-row per-tile LDS candidate cap (Poisson lambda~8)

typedef __attribute__((ext_vector_type(8))) short short8;   // bf16x8 fragment
typedef __attribute__((ext_vector_type(4))) float f32x4;
typedef __attribute__((ext_vector_type(4))) unsigned uint4v;

__device__ __forceinline__ ushort f2bf(float x) {           // RNE float->bf16
    unsigned b = __float_as_uint(x);
    return (ushort)((b + 0x7FFFu + ((b >> 16) & 1u)) >> 16);
}

__device__ __forceinline__ void async16(void* lds, const void* g) {
    __builtin_amdgcn_global_load_lds(
        (const __attribute__((address_space(1))) unsigned*)g,
        (__attribute__((address_space(3))) unsigned*)lds, 16, 0, 0);
}

// ---------------- K1: sumsq + cat argmax + bf16 hi/lo split + ccnt zero ---------------
__global__ void prep_kernel(const float* __restrict__ enc, const float* __restrict__ cat,
                            float* __restrict__ sq, float* __restrict__ maxg,
                            int* __restrict__ hard, ushort* __restrict__ eh,
                            ushort* __restrict__ el, int* __restrict__ ccnt) {
    int w = threadIdx.x >> 6, l = threadIdx.x & 63;
    int row = blockIdx.x * 4 + w;
    int gid = blockIdx.x * 256 + threadIdx.x;
    if (gid < BN) ccnt[gid] = 0;       // candidate counters re-zeroed every launch

    const float4* e4 = (const float4*)(enc + (size_t)row * ENC);
    float4 v = e4[l];  // elements 4l..4l+3
    float s = v.x * v.x + v.y * v.y + v.z * v.z + v.w * v.w;
    for (int m = 32; m; m >>= 1) s += __shfl_xor(s, m, 64);

    ushort4 hh, ll;
    hh.x = f2bf(v.x); ll.x = f2bf(v.x - __uint_as_float((unsigned)hh.x << 16));
    hh.y = f2bf(v.y); ll.y = f2bf(v.y - __uint_as_float((unsigned)hh.y << 16));
    hh.z = f2bf(v.z); ll.z = f2bf(v.z - __uint_as_float((unsigned)hh.z << 16));
    hh.w = f2bf(v.w); ll.w = f2bf(v.w - __uint_as_float((unsigned)hh.w << 16));
    int g = l >> 1;                                       // original granule 0..31
    int gs = (g & ~3) | ((g & 3) ^ ((row >> 1) & 3));     // swizzled within group-of-4
    int kp = gs * 8 + (l & 1) * 4;                        // element offset in row
    *(ushort4*)(eh + (size_t)row * ENC + kp) = hh;
    *(ushort4*)(el + (size_t)row * ENC + kp) = ll;

    float cv = (l < NCL) ? cat[(size_t)row * NCL + l] : -__builtin_huge_valf();
    int ci = (l < NCL) ? l : 0x7fffffff;
    for (int m = 32; m; m >>= 1) {
        float ov = __shfl_xor(cv, m, 64);
        int oi = __shfl_xor(ci, m, 64);
        if (ov > cv || (ov == cv && oi < ci)) { cv = ov; ci = oi; }
    }
    if (l == 0) { sq[row] = s; maxg[row] = cv; hard[row] = ci; }
}

// ---------------- K2: 256x256-tile fused split-bf16 MFMA d2 + candidate filter --------
// Round-14 lesson: A-direct-from-L2 regressed (L2 ~56 B/cyc/CU < LDS ~128) — the
// lever is LDS BYTES PER FLOP, not where A lives. This round: 8-wave 256x256
// block, 128x64 wave tile -> (8+4) frags x 2 planes = 384 B/lane per 1.57 MFLOP
// = 64 FLOP/B (r13: 48), stage-write bytes per FLOP halved. A+B both in LDS
// (r13 structure), 2-phase double buffer, d2 never materialized.
__global__ __launch_bounds__(512, 2)
void dist_mfma_kernel(const ushort* __restrict__ eh, const ushort* __restrict__ el,
                      const float* __restrict__ sq, int mode,
                      float* __restrict__ samp, const unsigned* __restrict__ piv,
                      unsigned* __restrict__ cval, int* __restrict__ cidxb,
                      int* __restrict__ ccnt) {
    __shared__ __align__(16) ushort lds0[2][4 * BM * BK];  // 2 bufs x 64KB (Ah Al Bh Bl)

    int t = threadIdx.x, l = t & 63;
    int w = t >> 6;
    int wm = w >> 2, wn = w & 3;       // 2x4 wave grid: wave tile 128x64

    int bx, by;
    if (mode) {  // column-strip XCD map: per-XCD B strip stays L2-resident
        int gx = gridDim.x;
        int bid = blockIdx.y * gx + blockIdx.x;
        int xcd = bid & 7, i = bid >> 3;
        int strip = gx >> 3;
        bx = xcd * strip + (i % strip);
        by = i / strip;
    } else { bx = blockIdx.x; by = blockIdx.y; }

    int gi0 = by * BM;                         // A rows
    int j0 = (mode ? 0 : SCOL) + bx * BM;      // B rows / d2 cols

    f32x4 acc[8][4];
#pragma unroll
    for (int m = 0; m < 8; ++m)
#pragma unroll
        for (int n = 0; n < 4; ++n) acc[m][n] = (f32x4){0.f, 0.f, 0.f, 0.f};

    int srow = t >> 2;                 // staging row 0..127 (+ q*128)
    int sg = (t & 3) * 8;              // granule elem offset within K-slice
    int il = l & 15;

#define STAGE(BUF, K0)                                                        \
    do {                                                                      \
        _Pragma("unroll") for (int q_ = 0; q_ < 2; ++q_) {                    \
            int r_ = srow + q_ * 128;                                         \
            size_t ga_ = (size_t)(gi0 + r_) * ENC + (K0) + sg;                \
            size_t gb_ = (size_t)(j0 + r_) * ENC + (K0) + sg;                 \
            int ldo_ = r_ * BK + sg;                                          \
            async16(&lds0[BUF][0 * BM * BK + ldo_], eh + ga_);                \
            async16(&lds0[BUF][1 * BM * BK + ldo_], el + ga_);                \
            async16(&lds0[BUF][2 * BM * BK + ldo_], eh + gb_);                \
            async16(&lds0[BUF][3 * BM * BK + ldo_], el + gb_);                \
        }                                                                     \
    } while (0)

    STAGE(0, 0);
    __syncthreads();                   // prologue: first tile ready

#pragma unroll
    for (int ks = 0; ks < 8; ++ks) {   // fully unrolled: static buf/reg indices
        int cb = ks & 1;
        if (ks + 1 < 8) STAGE(cb ^ 1, (ks + 1) * BK);   // issue next tile FIRST

        const ushort* Ah = &lds0[cb][0];
        const ushort* Al = Ah + BM * BK;
        const ushort* Bh = Ah + 2 * BM * BK;
        const ushort* Bl = Ah + 3 * BM * BK;

        short8 bh[4], bl4[4];
#pragma unroll
        for (int n = 0; n < 4; ++n) {
            int R = wn * 64 + n * 16 + il;
            int gl = (l >> 4) ^ ((R >> 1) & 3);       // un-swizzle on read
            bh[n]  = *(const short8*)(Bh + R * BK + gl * 8);
            bl4[n] = *(const short8*)(Bl + R * BK + gl * 8);
        }
#pragma unroll
        for (int m = 0; m < 8; ++m) {
            int Ra = wm * 128 + m * 16 + il;
            int gla = (l >> 4) ^ ((Ra >> 1) & 3);
            short8 am  = *(const short8*)(Ah + Ra * BK + gla * 8);
            short8 alm = *(const short8*)(Al + Ra * BK + gla * 8);
            // swapped operands: D[col=l&15 -> d2 row][reg -> d2 col]
#pragma unroll
            for (int n = 0; n < 4; ++n) {
                acc[m][n] = __builtin_amdgcn_mfma_f32_16x16x32_bf16(bh[n],  am,  acc[m][n], 0, 0, 0);
                acc[m][n] = __builtin_amdgcn_mfma_f32_16x16x32_bf16(bl4[n], am,  acc[m][n], 0, 0, 0);
                acc[m][n] = __builtin_amdgcn_mfma_f32_16x16x32_bf16(bh[n],  alm, acc[m][n], 0, 0, 0);
            }
        }

        __syncthreads();               // one barrier/step: drains next-tile loads
    }
#undef STAGE

    // epilogue: row = gi0 + wm*128 + m*16 + il; col = j0 + wn*64 + n*16 + q4 + r
    int q4 = (l >> 4) * 4;
    float sqi[8];
    float sqj[4][4];
#pragma unroll
    for (int m = 0; m < 8; ++m) sqi[m] = sq[gi0 + wm * 128 + m * 16 + il];
#pragma unroll
    for (int n = 0; n < 4; ++n)
#pragma unroll
        for (int r = 0; r < 4; ++r) sqj[n][r] = sq[j0 + wn * 64 + n * 16 + q4 + r];

    if (!mode) {
#pragma unroll
        for (int m = 0; m < 8; ++m)
#pragma unroll
            for (int n = 0; n < 4; ++n) {
                float4 o;
                o.x = fmaxf(sqi[m] + sqj[n][0] - 2.f * acc[m][n][0], 0.f);
                o.y = fmaxf(sqi[m] + sqj[n][1] - 2.f * acc[m][n][1], 0.f);
                o.z = fmaxf(sqi[m] + sqj[n][2] - 2.f * acc[m][n][2], 0.f);
                o.w = fmaxf(sqi[m] + sqj[n][3] - 2.f * acc[m][n][3], 0.f);
                int row = gi0 + wm * 128 + m * 16 + il;
                int jc = j0 + wn * 64 + n * 16 + q4;
                *(float4*)(samp + (size_t)row * SN + (jc - SCOL)) = o;
            }
        return;
    }

    // ---- mode 1: LDS-aggregated candidate flush (overlay on idle staging LDS) ----
    int* rcnt = (int*)&lds0[0][0];                 // [256] per-local-row counts
    int* rbase = rcnt + BM;                        // [256] reserved global bases
    unsigned* bval = (unsigned*)(rbase + BM);      // [256][RCAP]
    int* bidx = (int*)(bval + BM * RCAP);          // [256][RCAP]  (total ~50 KB)

    if (t < BM) rcnt[t] = 0;
    unsigned pv[8];
#pragma unroll
    for (int m = 0; m < 8; ++m) pv[m] = piv[gi0 + wm * 128 + m * 16 + il];
    __syncthreads();                   // rcnt zeroed; K-loop LDS reads long done

#pragma unroll
    for (int m = 0; m < 8; ++m)
#pragma unroll
        for (int n = 0; n < 4; ++n) {
            int lr = wm * 128 + m * 16 + il;       // local row 0..255
            int jc = j0 + wn * 64 + n * 16 + q4;
#pragma unroll
            for (int r = 0; r < 4; ++r) {
                float o = fmaxf(sqi[m] + sqj[n][r] - 2.f * acc[m][n][r], 0.f);
                unsigned ub = __float_as_uint(o);
                if (ub < pv[m]) {                  // ~4 hits/thread: LDS atomic
                    int pos = atomicAdd(&rcnt[lr], 1);
                    if (pos < RCAP) {
                        bval[lr * RCAP + pos] = ub;
                        bidx[lr * RCAP + pos] = jc + r;
                    } else {                       // overflow ~never: direct, exact
                        int slot = atomicAdd(&ccnt[gi0 + lr], 1);
                        if (slot < CCAP) {
                            cval[(size_t)(gi0 + lr) * CCAP + slot] = ub;
                            cidxb[(size_t)(gi0 + lr) * CCAP + slot] = jc + r;
                        }
                    }
                }
            }
        }
    __syncthreads();

    if (t < BM) {                      // 256 PARALLEL global atomics (latency overlap)
        int c = rcnt[t]; if (c > RCAP) c = RCAP;
        rbase[t] = c ? atomicAdd(&ccnt[gi0 + t], c) : 0;
    }
    __syncthreads();

    {                                  // coalesced copy-out: 2 threads per row
        int lr = t >> 1;
        int c = rcnt[lr]; if (c > RCAP) c = RCAP;
        int b = rbase[lr];
        for (int e = t & 1; e < c; e += 2) {
            int s = b + e;
            if (s < CCAP) {
                cval[(size_t)(gi0 + lr) * CCAP + s] = bval[lr * RCAP + e];
                cidxb[(size_t)(gi0 + lr) * CCAP + s] = bidx[lr * RCAP + e];
            }
        }
    }
}

// ---------------- K2b: per-row pivot = rank-r of 256 sampled d2 -----------------------
__global__ void pivot_kernel(const float* __restrict__ samp, const int* __restrict__ kptr,
                             unsigned* __restrict__ piv) {
    int w = threadIdx.x >> 6, l = threadIdx.x & 63;
    int row = blockIdx.x * 4 + w;
    const uint4v* rd = (const uint4v*)(samp + (size_t)row * SN);
    uint4v sv = rd[l];

    int topn = *kptr + 1;
    int r = topn / 16 + 1; if (r < 8) r = 8;   // E[row count] ~ 32r ~ 255

    unsigned lo = 0u, hi = 0x7F800000u;        // d2 >= 0: uint order == float order
    while (lo < hi) {                          // wave-uniform, no block sync
        unsigned mid = lo + ((hi - lo) >> 1);
        int c = 0;
#pragma unroll
        for (int e = 0; e < 4; ++e) c += __popcll(__ballot(sv[e] <= mid));
        if (c >= r) hi = mid; else lo = mid + 1;
    }
    if (l == 0) piv[row] = lo;
}

// ---------------- K3: exact rank-26 among candidates + bins + entropy -----------------
__global__ __launch_bounds__(256, 2)
void select_kernel(const unsigned* __restrict__ cval, const int* __restrict__ cidxb,
                   const int* __restrict__ ccnt, const unsigned* __restrict__ piv,
                   const float* __restrict__ enc, const float* __restrict__ sq,
                   const float* __restrict__ maxg, const int* __restrict__ hard,
                   const int* __restrict__ kptr, float* __restrict__ out) {
    __shared__ __align__(16) unsigned sval[CCAP];
    __shared__ int sidx[CCAP];
    __shared__ __align__(16) unsigned rowbuf[BN];   // fallback only (32 KB)
    __shared__ __align__(16) float encrow[ENC];
    __shared__ int scnt[2][4];
    __shared__ int sbins[NCL];

    int t = threadIdx.x, w = t >> 6, l = t & 63;
    int li = blockIdx.x;
    if (t < NCL) sbins[t] = 0;

    int topn = *kptr + 1;              // 26: thr = sorted[k]
    int nc = ccnt[li];
    bool ok = (nc >= topn) && (nc <= CCAP);
    unsigned thr;

    if (ok) {
#pragma unroll
        for (int k2 = 0; k2 < 4; ++k2) sval[t + k2 * 256] = 0xFFFFFFFFu;  // pad
        for (int pos = t; pos < nc; pos += 256) {     // same-thread slots: no race
            sval[pos] = cval[(size_t)li * CCAP + pos];
            sidx[pos] = cidxb[(size_t)li * CCAP + pos];
        }
        __syncthreads();

        int pp = 0;
        unsigned lo = 0u, hi = piv[li];               // all candidates < piv
        while (lo < hi) {
            unsigned mid = lo + ((hi - lo) >> 1);
            uint4v cv = ((const uint4v*)sval)[t];     // 1 ds_read_b128/thread/probe
            int cnt = 0;
#pragma unroll
            for (int c = 0; c < 4; ++c) cnt += __popcll(__ballot(cv[c] <= mid));
            if (l == 0) scnt[pp][w] = cnt;
            __syncthreads();                          // parity slots: 1 barrier/probe
            int tot = scnt[pp][0] + scnt[pp][1] + scnt[pp][2] + scnt[pp][3];
            if (tot >= topn) hi = mid; else lo = mid + 1;
            pp ^= 1;
        }
        thr = lo;

        for (int pos = t; pos < nc; pos += 256)
            if (sval[pos] < thr) atomicAdd(&sbins[hard[sidx[pos]]], 1);
    } else {
        // exact fallback: fp32 full-row recompute + block bisection (round-9 proven)
        if (t < 64) ((float4*)encrow)[t] = ((const float4*)(enc + (size_t)li * ENC))[t];
        __syncthreads();
        float sqi = sq[li];
        for (int c0 = 0; c0 < BN; c0 += 256) {
            int c = c0 + t;
            const float* ec = enc + (size_t)c * ENC;
            float dot = 0.f;
            for (int d = 0; d < ENC; ++d) dot = fmaf(encrow[d], ec[d], dot);
            rowbuf[c] = __float_as_uint(fmaxf(sqi + sq[c] - 2.f * dot, 0.f));
        }
        __syncthreads();

        int pp = 0;
        unsigned lo = 0u, hi = 0x7F800000u;
        while (lo < hi) {
            unsigned mid = lo + ((hi - lo) >> 1);
            int cnt = 0;
#pragma unroll
            for (int q = 0; q < 8; ++q) {
                uint4v u = ((const uint4v*)rowbuf)[q * 256 + t];
#pragma unroll
                for (int c = 0; c < 4; ++c) cnt += __popcll(__ballot(u[c] <= mid));
            }
            if (l == 0) scnt[pp][w] = cnt;
            __syncthreads();
            int tot = scnt[pp][0] + scnt[pp][1] + scnt[pp][2] + scnt[pp][3];
            if (tot >= topn) hi = mid; else lo = mid + 1;
            pp ^= 1;
        }
        thr = lo;

#pragma unroll
        for (int q = 0; q < 8; ++q) {
            uint4v u = ((const uint4v*)rowbuf)[q * 256 + t];
#pragma unroll
            for (int c = 0; c < 4; ++c)
                if (u[c] < thr)
                    atomicAdd(&sbins[hard[(q * 256 + t) * 4 + c]], 1);
        }
    }
    __syncthreads();

    // entropy epilogue: wave 0, lanes 0..31 = clusters
    if (t < NCL) {
        int cnt = sbins[t];
        int n = cnt;
        for (int m = 16; m; m >>= 1) n += __shfl_xor(n, m, 64);
        float nf = (float)n;
        float b = (float)cnt / nf;
        float term = -b * logf(b + 1e-5f);
        for (int m = 16; m; m >>= 1) term += __shfl_xor(term, m, 64);
        if (t == 0) out[li] = term * maxg[li];
    }
}

extern "C" void kernel_launch(void* const* d_in, const int* in_sizes, int n_in,
                              void* d_out, int out_size, void* d_ws, size_t ws_size,
                              hipStream_t stream) {
    const float* enc = (const float*)d_in[0];
    const float* cat = (const float*)d_in[1];
    const int* kptr = (const int*)d_in[2];
    float* out = (float*)d_out;

    float* sq = (float*)d_ws;                               // 32 KB
    float* maxg = sq + BN;                                  // 32 KB
    int* hard = (int*)(maxg + BN);                          // 32 KB
    ushort* eh = (ushort*)(hard + BN);                      // 4 MB
    ushort* el = eh + (size_t)BN * ENC;                     // 4 MB
    float* samp = (float*)(el + (size_t)BN * ENC);          // 8 MB
    unsigned* piv = (unsigned*)(samp + (size_t)BN * SN);    // 32 KB
    int* ccnt = (int*)(piv + BN);                           // 32 KB
    unsigned* cval = (unsigned*)(ccnt + BN);                // 32 MB
    int* cidxb = (int*)(cval + (size_t)BN * CCAP);          // 32 MB

    prep_kernel<<<BN / 4, 256, 0, stream>>>(enc, cat, sq, maxg, hard, eh, el, ccnt);

    dim3 gs(SN / BM, BN / BM);        // sample pass: 1 x 32 tiles
    dist_mfma_kernel<<<gs, 512, 0, stream>>>(eh, el, sq, 0, samp, piv, cval, cidxb, ccnt);

    pivot_kernel<<<BN / 4, 256, 0, stream>>>(samp, kptr, piv);

    dim3 gm(BN / BM, BN / BM);        // main pass: 32 x 32 tiles, no d2 store
    dist_mfma_kernel<<<gm, 512, 0, stream>>>(eh, el, sq, 1, samp, piv, cval, cidxb, ccnt);

    select_kernel<<<BN, 256, 0, stream>>>(cval, cidxb, ccnt, piv, enc, sq,
                                          maxg, hard, kptr, out);
}

// Round 16
// 258.371 us; speedup vs baseline: 1.2207x; 1.2206x over previous
//
#include <hip/hip_runtime.h>
#include <math.h>

#define BN 8192
#define ENC 256
#define NCL 32
#define BM 256      // block tile 256x256, 8 waves 2x4, wave tile 128x64
#define BK 32
#define CCAP 1024
#define SCOL 2048   // sample column base
#define SN 256      // sample column count
#define RCAP 24     // per-row per-tile LDS candidate cap

typedef __attribute__((ext_vector_type(8))) short short8;   // bf16x8 fragment
typedef __attribute__((ext_vector_type(4))) float f32x4;
typedef __attribute__((ext_vector_type(4))) unsigned uint4v;

__device__ __forceinline__ ushort f2bf(float x) {           // RNE float->bf16
    unsigned b = __float_as_uint(x);
    return (ushort)((b + 0x7FFFu + ((b >> 16) & 1u)) >> 16);
}

__device__ __forceinline__ void async16(void* lds, const void* g) {
    __builtin_amdgcn_global_load_lds(
        (const __attribute__((address_space(1))) unsigned*)g,
        (__attribute__((address_space(3))) unsigned*)lds, 16, 0, 0);
}

// ---------------- K1: sumsq + cat argmax + bf16 hi/lo split + ccnt zero ---------------
__global__ void prep_kernel(const float* __restrict__ enc, const float* __restrict__ cat,
                            float* __restrict__ sq, float* __restrict__ maxg,
                            int* __restrict__ hard, ushort* __restrict__ eh,
                            ushort* __restrict__ el, int* __restrict__ ccnt) {
    int w = threadIdx.x >> 6, l = threadIdx.x & 63;
    int row = blockIdx.x * 4 + w;
    int gid = blockIdx.x * 256 + threadIdx.x;
    if (gid < BN) ccnt[gid] = 0;

    const float4* e4 = (const float4*)(enc + (size_t)row * ENC);
    float4 v = e4[l];
    float s = v.x * v.x + v.y * v.y + v.z * v.z + v.w * v.w;
    for (int m = 32; m; m >>= 1) s += __shfl_xor(s, m, 64);

    ushort4 hh, ll;
    hh.x = f2bf(v.x); ll.x = f2bf(v.x - __uint_as_float((unsigned)hh.x << 16));
    hh.y = f2bf(v.y); ll.y = f2bf(v.y - __uint_as_float((unsigned)hh.y << 16));
    hh.z = f2bf(v.z); ll.z = f2bf(v.z - __uint_as_float((unsigned)hh.z << 16));
    hh.w = f2bf(v.w); ll.w = f2bf(v.w - __uint_as_float((unsigned)hh.w << 16));
    int g = l >> 1;
    int gs = (g & ~3) | ((g & 3) ^ ((row >> 1) & 3));     // granule swizzle (rule #21)
    int kp = gs * 8 + (l & 1) * 4;
    *(ushort4*)(eh + (size_t)row * ENC + kp) = hh;
    *(ushort4*)(el + (size_t)row * ENC + kp) = ll;

    float cv = (l < NCL) ? cat[(size_t)row * NCL + l] : -__builtin_huge_valf();
    int ci = (l < NCL) ? l : 0x7fffffff;
    for (int m = 32; m; m >>= 1) {
        float ov = __shfl_xor(cv, m, 64);
        int oi = __shfl_xor(ci, m, 64);
        if (ov > cv || (ov == cv && oi < ci)) { cv = ov; ci = oi; }
    }
    if (l == 0) { sq[row] = s; maxg[row] = cv; hard[row] = ci; }
}

// ---------------- K2: 8-phase-scheduled fused split-bf16 MFMA d2 + filter -------------
// Round-15: 2-phase lockstep = catalog's ~650-TF ceiling (LDS reads and MFMA
// serialize; MfmaUtil 27%). This round ports the m201 8-phase template: per
// K-tile, 4 phases of {ds_read A-pair (+B in p0) | stage (p0/p1) | s_barrier |
// lgkmcnt(0)+sched_barrier | setprio(1) 24 MFMA setprio(0) | s_barrier};
// vmcnt(0) waits only after p3's MFMA (staged loads fly ~3 phases, not drained
// per-step by __syncthreads). Dual barrier per phase = race-safe template.
__global__ __launch_bounds__(512, 2)
void dist_mfma_kernel(const ushort* __restrict__ eh, const ushort* __restrict__ el,
                      const float* __restrict__ sq, int mode,
                      float* __restrict__ samp, const unsigned* __restrict__ piv,
                      unsigned* __restrict__ cval, int* __restrict__ cidxb,
                      int* __restrict__ ccnt) {
    __shared__ __align__(16) ushort lds0[2][4 * BM * BK];  // 2 bufs x 64KB (Ah Al Bh Bl)

    int t = threadIdx.x, l = t & 63;
    int w = t >> 6;
    int wm = w >> 2, wn = w & 3;       // 2x4 wave grid: wave tile 128x64

    int bx, by;
    if (mode) {  // column-strip XCD map: per-XCD A panel + B strip stay L2-resident
        int gx = gridDim.x;
        int bid = blockIdx.y * gx + blockIdx.x;
        int xcd = bid & 7, i = bid >> 3;
        int strip = gx >> 3;
        bx = xcd * strip + (i % strip);
        by = i / strip;
    } else { bx = blockIdx.x; by = blockIdx.y; }

    int gi0 = by * BM;                         // A rows
    int j0 = (mode ? 0 : SCOL) + bx * BM;      // B rows / d2 cols

    f32x4 acc[8][4];
#pragma unroll
    for (int m = 0; m < 8; ++m)
#pragma unroll
        for (int n = 0; n < 4; ++n) acc[m][n] = (f32x4){0.f, 0.f, 0.f, 0.f};

    int srow = t >> 2;                 // staging row 0..127 (+128 for q=1)
    int sg = (t & 3) * 8;              // granule elem offset within K-slice
    int il = l & 15;

    // 4 async16: A planes (hi+lo), both row-halves, for tile at K0 into buf BUF
#define STAGE_A(BUF, K0)                                                      \
    do {                                                                      \
        _Pragma("unroll") for (int q_ = 0; q_ < 2; ++q_) {                    \
            int r_ = srow + q_ * 128;                                         \
            size_t ga_ = (size_t)(gi0 + r_) * ENC + (K0) + sg;                \
            int ldo_ = r_ * BK + sg;                                          \
            async16(&lds0[BUF][0 * BM * BK + ldo_], eh + ga_);                \
            async16(&lds0[BUF][1 * BM * BK + ldo_], el + ga_);                \
        }                                                                     \
    } while (0)
#define STAGE_B(BUF, K0)                                                      \
    do {                                                                      \
        _Pragma("unroll") for (int q_ = 0; q_ < 2; ++q_) {                    \
            int r_ = srow + q_ * 128;                                         \
            size_t gb_ = (size_t)(j0 + r_) * ENC + (K0) + sg;                 \
            int ldo_ = r_ * BK + sg;                                          \
            async16(&lds0[BUF][2 * BM * BK + ldo_], eh + gb_);                \
            async16(&lds0[BUF][3 * BM * BK + ldo_], el + gb_);                \
        }                                                                     \
    } while (0)

#define READ_APAIR(PH, AHp, ALp)                                              \
    short8 a##PH##h0, a##PH##h1, a##PH##l0, a##PH##l1;                        \
    do {                                                                      \
        int Ra0 = wm * 128 + (2 * PH) * 16 + il;                              \
        int Ra1 = Ra0 + 16;                                                   \
        int g0 = (l >> 4) ^ ((Ra0 >> 1) & 3);                                 \
        int g1 = (l >> 4) ^ ((Ra1 >> 1) & 3);                                 \
        a##PH##h0 = *(const short8*)(AHp + Ra0 * BK + g0 * 8);                \
        a##PH##h1 = *(const short8*)(AHp + Ra1 * BK + g1 * 8);                \
        a##PH##l0 = *(const short8*)(ALp + Ra0 * BK + g0 * 8);                \
        a##PH##l1 = *(const short8*)(ALp + Ra1 * BK + g1 * 8);                \
    } while (0)

#define CLUSTER(PH)                                                           \
    do {                                                                      \
        _Pragma("unroll") for (int n_ = 0; n_ < 4; ++n_) {                    \
            acc[2*PH][n_]   = __builtin_amdgcn_mfma_f32_16x16x32_bf16(bh[n_],  a##PH##h0, acc[2*PH][n_],   0, 0, 0); \
            acc[2*PH][n_]   = __builtin_amdgcn_mfma_f32_16x16x32_bf16(bl4[n_], a##PH##h0, acc[2*PH][n_],   0, 0, 0); \
            acc[2*PH][n_]   = __builtin_amdgcn_mfma_f32_16x16x32_bf16(bh[n_],  a##PH##l0, acc[2*PH][n_],   0, 0, 0); \
            acc[2*PH+1][n_] = __builtin_amdgcn_mfma_f32_16x16x32_bf16(bh[n_],  a##PH##h1, acc[2*PH+1][n_], 0, 0, 0); \
            acc[2*PH+1][n_] = __builtin_amdgcn_mfma_f32_16x16x32_bf16(bl4[n_], a##PH##h1, acc[2*PH+1][n_], 0, 0, 0); \
            acc[2*PH+1][n_] = __builtin_amdgcn_mfma_f32_16x16x32_bf16(bh[n_],  a##PH##l1, acc[2*PH+1][n_], 0, 0, 0); \
        }                                                                     \
    } while (0)

#define BAR()     __builtin_amdgcn_s_barrier()
#define LGKM0()   do { asm volatile("s_waitcnt lgkmcnt(0)" ::: "memory");     \
                       __builtin_amdgcn_sched_barrier(0); } while (0)
#define VM0()     asm volatile("s_waitcnt vmcnt(0)" ::: "memory")

    // prologue: stage tile 0 fully, drain, sync
    STAGE_A(0, 0);
    STAGE_B(0, 0);
    __syncthreads();                   // drains vmcnt(0): tile 0 resident

#pragma unroll
    for (int ks = 0; ks < 8; ++ks) {
        const int cb = ks & 1, nb = cb ^ 1;
        const ushort* Ah = &lds0[cb][0];
        const ushort* Al = Ah + BM * BK;
        const ushort* Bh = Ah + 2 * BM * BK;
        const ushort* Bl = Ah + 3 * BM * BK;

        short8 bh[4], bl4[4];
        // ---- phase 0: read B + A-pair0; stage A(t+1); MFMA m0,m1 ----
#pragma unroll
        for (int n = 0; n < 4; ++n) {
            int R = wn * 64 + n * 16 + il;
            int gl = (l >> 4) ^ ((R >> 1) & 3);
            bh[n]  = *(const short8*)(Bh + R * BK + gl * 8);
            bl4[n] = *(const short8*)(Bl + R * BK + gl * 8);
        }
        READ_APAIR(0, Ah, Al);
        if (ks + 1 < 8) STAGE_A(nb, (ks + 1) * BK);
        BAR(); LGKM0();
        __builtin_amdgcn_s_setprio(1); CLUSTER(0); __builtin_amdgcn_s_setprio(0);
        BAR();
        // ---- phase 1: read A-pair1; stage B(t+1); MFMA m2,m3 ----
        READ_APAIR(1, Ah, Al);
        if (ks + 1 < 8) STAGE_B(nb, (ks + 1) * BK);
        BAR(); LGKM0();
        __builtin_amdgcn_s_setprio(1); CLUSTER(1); __builtin_amdgcn_s_setprio(0);
        BAR();
        // ---- phase 2: read A-pair2; MFMA m4,m5 ----
        READ_APAIR(2, Ah, Al);
        BAR(); LGKM0();
        __builtin_amdgcn_s_setprio(1); CLUSTER(2); __builtin_amdgcn_s_setprio(0);
        BAR();
        // ---- phase 3: read A-pair3; MFMA m6,m7; LATE vmcnt; barrier ----
        READ_APAIR(3, Ah, Al);
        BAR(); LGKM0();
        __builtin_amdgcn_s_setprio(1); CLUSTER(3); __builtin_amdgcn_s_setprio(0);
        if (ks + 1 < 8) VM0();         // t+1's loads had ~3 phases in flight
        BAR();
    }
#undef STAGE_A
#undef STAGE_B
#undef READ_APAIR
#undef CLUSTER

    // epilogue: row = gi0 + wm*128 + m*16 + il; col = j0 + wn*64 + n*16 + q4 + r
    int q4 = (l >> 4) * 4;
    float sqi[8];
    float sqj[4][4];
#pragma unroll
    for (int m = 0; m < 8; ++m) sqi[m] = sq[gi0 + wm * 128 + m * 16 + il];
#pragma unroll
    for (int n = 0; n < 4; ++n)
#pragma unroll
        for (int r = 0; r < 4; ++r) sqj[n][r] = sq[j0 + wn * 64 + n * 16 + q4 + r];

    if (!mode) {
#pragma unroll
        for (int m = 0; m < 8; ++m)
#pragma unroll
            for (int n = 0; n < 4; ++n) {
                float4 o;
                o.x = fmaxf(sqi[m] + sqj[n][0] - 2.f * acc[m][n][0], 0.f);
                o.y = fmaxf(sqi[m] + sqj[n][1] - 2.f * acc[m][n][1], 0.f);
                o.z = fmaxf(sqi[m] + sqj[n][2] - 2.f * acc[m][n][2], 0.f);
                o.w = fmaxf(sqi[m] + sqj[n][3] - 2.f * acc[m][n][3], 0.f);
                int row = gi0 + wm * 128 + m * 16 + il;
                int jc = j0 + wn * 64 + n * 16 + q4;
                *(float4*)(samp + (size_t)row * SN + (jc - SCOL)) = o;
            }
        return;
    }

    // ---- mode 1: LDS-aggregated candidate flush (r13-proven) ----
    int* rcnt = (int*)&lds0[0][0];                 // [256] per-local-row counts
    int* rbase = rcnt + BM;                        // [256] reserved global bases
    unsigned* bval = (unsigned*)(rbase + BM);      // [256][RCAP]
    int* bidx = (int*)(bval + BM * RCAP);          // [256][RCAP]

    if (t < BM) rcnt[t] = 0;
    unsigned pv[8];
#pragma unroll
    for (int m = 0; m < 8; ++m) pv[m] = piv[gi0 + wm * 128 + m * 16 + il];
    __syncthreads();

#pragma unroll
    for (int m = 0; m < 8; ++m)
#pragma unroll
        for (int n = 0; n < 4; ++n) {
            int lr = wm * 128 + m * 16 + il;
            int jc = j0 + wn * 64 + n * 16 + q4;
#pragma unroll
            for (int r = 0; r < 4; ++r) {
                float o = fmaxf(sqi[m] + sqj[n][r] - 2.f * acc[m][n][r], 0.f);
                unsigned ub = __float_as_uint(o);
                if (ub < pv[m]) {
                    int pos = atomicAdd(&rcnt[lr], 1);
                    if (pos < RCAP) {
                        bval[lr * RCAP + pos] = ub;
                        bidx[lr * RCAP + pos] = jc + r;
                    } else {                       // overflow ~never: direct, exact
                        int slot = atomicAdd(&ccnt[gi0 + lr], 1);
                        if (slot < CCAP) {
                            cval[(size_t)(gi0 + lr) * CCAP + slot] = ub;
                            cidxb[(size_t)(gi0 + lr) * CCAP + slot] = jc + r;
                        }
                    }
                }
            }
        }
    __syncthreads();

    if (t < BM) {                      // 256 parallel global atomics
        int c = rcnt[t]; if (c > RCAP) c = RCAP;
        rbase[t] = c ? atomicAdd(&ccnt[gi0 + t], c) : 0;
    }
    __syncthreads();

    {                                  // coalesced copy-out: 2 threads per row
        int lr = t >> 1;
        int c = rcnt[lr]; if (c > RCAP) c = RCAP;
        int b = rbase[lr];
        for (int e = t & 1; e < c; e += 2) {
            int s = b + e;
            if (s < CCAP) {
                cval[(size_t)(gi0 + lr) * CCAP + s] = bval[lr * RCAP + e];
                cidxb[(size_t)(gi0 + lr) * CCAP + s] = bidx[lr * RCAP + e];
            }
        }
    }
}

// ---------------- K2b: per-row pivot = rank-r of 256 sampled d2 -----------------------
__global__ void pivot_kernel(const float* __restrict__ samp, const int* __restrict__ kptr,
                             unsigned* __restrict__ piv) {
    int w = threadIdx.x >> 6, l = threadIdx.x & 63;
    int row = blockIdx.x * 4 + w;
    const uint4v* rd = (const uint4v*)(samp + (size_t)row * SN);
    uint4v sv = rd[l];

    int topn = *kptr + 1;
    int r = topn / 16 + 1; if (r < 8) r = 8;   // E[row count] ~ 32r ~ 255

    unsigned lo = 0u, hi = 0x7F800000u;
    while (lo < hi) {                          // wave-uniform
        unsigned mid = lo + ((hi - lo) >> 1);
        int c = 0;
#pragma unroll
        for (int e = 0; e < 4; ++e) c += __popcll(__ballot(sv[e] <= mid));
        if (c >= r) hi = mid; else lo = mid + 1;
    }
    if (l == 0) piv[row] = lo;
}

// ---------------- K3: wave-per-row exact rank select (barrier-free fast path) ---------
// One wave per row: <=16 candidates/lane in static-indexed regs, ballot bisect,
// no block barriers. Rare bad rows (nc<topn or >CCAP) fall back to the proven
// block-cooperative fp32 recompute afterward.
__global__ __launch_bounds__(256, 2)
void select_kernel(const unsigned* __restrict__ cval, const int* __restrict__ cidxb,
                   const int* __restrict__ ccnt, const unsigned* __restrict__ piv,
                   const float* __restrict__ enc, const float* __restrict__ sq,
                   const float* __restrict__ maxg, const int* __restrict__ hard,
                   const int* __restrict__ kptr, float* __restrict__ out) {
    __shared__ __align__(16) unsigned rowbuf[BN];   // fallback only (32 KB)
    __shared__ __align__(16) float encrow[ENC];
    __shared__ int scnt[2][4];
    __shared__ int sbins[4][NCL];
    __shared__ int sfail;

    int t = threadIdx.x, w = t >> 6, l = t & 63;
    int li = blockIdx.x * 4 + w;       // one wave per row
    if (t == 0) sfail = 0;
    if (l < NCL) sbins[w][l] = 0;
    __syncthreads();

    int topn = *kptr + 1;              // 26: thr = sorted[k]
    int nc = ccnt[li];
    bool ok = (nc >= topn) && (nc <= CCAP);

    if (ok) {
        unsigned cv[16]; int cidx[16];
#pragma unroll
        for (int j = 0; j < 16; ++j) {         // static indices: stays in VGPRs
            int idx = j * 64 + l;
            bool v = idx < nc;
            cv[j]   = v ? cval[(size_t)li * CCAP + idx] : 0xFFFFFFFFu;
            cidx[j] = v ? cidxb[(size_t)li * CCAP + idx] : 0;
        }
        unsigned lo = 0u, hi = piv[li];        // all candidates < piv
        while (lo < hi) {                      // wave-uniform: zero barriers
            unsigned mid = lo + ((hi - lo) >> 1);
            int cnt = 0;
#pragma unroll
            for (int j = 0; j < 16; ++j) cnt += __popcll(__ballot(cv[j] <= mid));
            if (cnt >= topn) hi = mid; else lo = mid + 1;
        }
#pragma unroll
        for (int j = 0; j < 16; ++j)
            if (cv[j] < lo) atomicAdd(&sbins[w][hard[cidx[j]]], 1);
    } else {
        if (l == 0) atomicOr(&sfail, 1 << w);
    }
    __syncthreads();
    int fmask = sfail;                 // block-uniform

    // exact fallback per failed row (~never): fp32 recompute + block bisection
    for (int fw = 0; fw < 4; ++fw) if (fmask & (1 << fw)) {
        int li2 = blockIdx.x * 4 + fw;
        if (t < 64) ((float4*)encrow)[t] = ((const float4*)(enc + (size_t)li2 * ENC))[t];
        __syncthreads();
        float sqi = sq[li2];
        for (int c0 = 0; c0 < BN; c0 += 256) {
            int c = c0 + t;
            const float* ec = enc + (size_t)c * ENC;
            float dot = 0.f;
            for (int d = 0; d < ENC; ++d) dot = fmaf(encrow[d], ec[d], dot);
            rowbuf[c] = __float_as_uint(fmaxf(sqi + sq[c] - 2.f * dot, 0.f));
        }
        __syncthreads();
        int pp = 0;
        unsigned lo = 0u, hi = 0x7F800000u;
        while (lo < hi) {
            unsigned mid = lo + ((hi - lo) >> 1);
            int cnt = 0;
#pragma unroll
            for (int q = 0; q < 8; ++q) {
                uint4v u = ((const uint4v*)rowbuf)[q * 256 + t];
#pragma unroll
                for (int c = 0; c < 4; ++c) cnt += __popcll(__ballot(u[c] <= mid));
            }
            if (l == 0) scnt[pp][w] = cnt;
            __syncthreads();
            int tot = scnt[pp][0] + scnt[pp][1] + scnt[pp][2] + scnt[pp][3];
            if (tot >= topn) hi = mid; else lo = mid + 1;
            pp ^= 1;
        }
#pragma unroll
        for (int q = 0; q < 8; ++q) {
            uint4v u = ((const uint4v*)rowbuf)[q * 256 + t];
#pragma unroll
            for (int c = 0; c < 4; ++c)
                if (u[c] < lo)
                    atomicAdd(&sbins[fw][hard[(q * 256 + t) * 4 + c]], 1);
        }
        __syncthreads();
    }

    // entropy epilogue: lanes 0..31 of each wave = clusters of its row
    if (l < NCL) {
        int cnt = sbins[w][l];
        int n = cnt;
        for (int m = 16; m; m >>= 1) n += __shfl_xor(n, m, 64);
        float nf = (float)n;
        float b = (float)cnt / nf;
        float term = -b * logf(b + 1e-5f);
        for (int m = 16; m; m >>= 1) term += __shfl_xor(term, m, 64);
        if (l == 0) out[li] = term * maxg[li];
    }
}

extern "C" void kernel_launch(void* const* d_in, const int* in_sizes, int n_in,
                              void* d_out, int out_size, void* d_ws, size_t ws_size,
                              hipStream_t stream) {
    const float* enc = (const float*)d_in[0];
    const float* cat = (const float*)d_in[1];
    const int* kptr = (const int*)d_in[2];
    float* out = (float*)d_out;

    float* sq = (float*)d_ws;                               // 32 KB
    float* maxg = sq + BN;                                  // 32 KB
    int* hard = (int*)(maxg + BN);                          // 32 KB
    ushort* eh = (ushort*)(hard + BN);                      // 4 MB
    ushort* el = eh + (size_t)BN * ENC;                     // 4 MB
    float* samp = (float*)(el + (size_t)BN * ENC);          // 8 MB
    unsigned* piv = (unsigned*)(samp + (size_t)BN * SN);    // 32 KB
    int* ccnt = (int*)(piv + BN);                           // 32 KB
    unsigned* cval = (unsigned*)(ccnt + BN);                // 32 MB
    int* cidxb = (int*)(cval + (size_t)BN * CCAP);          // 32 MB

    prep_kernel<<<BN / 4, 256, 0, stream>>>(enc, cat, sq, maxg, hard, eh, el, ccnt);

    dim3 gs(SN / BM, BN / BM);        // sample pass: 1 x 32 tiles
    dist_mfma_kernel<<<gs, 512, 0, stream>>>(eh, el, sq, 0, samp, piv, cval, cidxb, ccnt);

    pivot_kernel<<<BN / 4, 256, 0, stream>>>(samp, kptr, piv);

    dim3 gm(BN / BM, BN / BM);        // main pass: 32 x 32 tiles, no d2 store
    dist_mfma_kernel<<<gm, 512, 0, stream>>>(eh, el, sq, 1, samp, piv, cval, cidxb, ccnt);

    select_kernel<<<BN / 4, 256, 0, stream>>>(cval, cidxb, ccnt, piv, enc, sq,
                                              maxg, hard, kptr, out);
}